// Round 1
// baseline (159.081 us; speedup 1.0000x reference)
//
#include <hip/hip_runtime.h>
#include <stdint.h>

#define N_NODES 8192
#define IN_F    256
#define HD      64
#define NH      2
#define MS      4      // m-splits per row-block
#define ALPHA   0.2f

typedef __attribute__((ext_vector_type(8))) short bf16x8s;
typedef __attribute__((ext_vector_type(4))) float f32x4;

// ws layout (bytes)
#define OFF_U      0          // u[h][v][256] f32                   : 4 KB
#define OFF_WFRAG  4096       // W frag-order [8][8][64][8] bf16    : 64 KB
#define OFF_F1     69632      // f1[2][8192] f32                    : 64 KB
#define OFF_F2     135168     // f2[2][8192] f32                    : 64 KB
#define OFF_F2MAX  200704     // f2max[2] f32 (+pad)
#define OFF_WHB    200960     // Wh frag-order [2][128][2][4][64][8] bf16 : 2 MB
#define OFF_OP     2298112    // O partials [MS][2][8192][64] f32   : 16 MB
#define OFF_LP     19075328   // L partials [MS][2][8192] f32       : 256 KB

__device__ __forceinline__ unsigned short f2bf(float x) {
  union { float f; uint32_t u; } c; c.f = x;
  uint32_t r = c.u + 0x7FFFu + ((c.u >> 16) & 1u);   // RNE
  return (unsigned short)(r >> 16);
}

// ---------------- kernel 1: u = W·a (f32) + W repacked to B-fragment order (bf16)
__global__ void gat_prep_kernel(const float* __restrict__ W, const float* __restrict__ a,
                                float* __restrict__ u, unsigned short* __restrict__ wfrag)
{
  int t = threadIdx.x;
  for (int idx = t; idx < NH * 2 * IN_F; idx += 256) {
    int i = idx & 255, v = (idx >> 8) & 1, h = idx >> 9;
    const float* Wp = W + (size_t)(h * IN_F + i) * HD;
    const float* ap = a + h * 2 * HD + v * HD;
    float s = 0.f;
    for (int d = 0; d < HD; ++d) s += Wp[d] * ap[d];
    u[(h * 2 + v) * IN_F + i] = s;
  }
  // wfrag[Dt(8)][ks(8)][lane(64)][j(8)]: B[k][col] with k=ks*32+(lane>>4)*8+j, col=lane&15
  for (int idx = t; idx < 8 * 8 * 64 * 8; idx += 256) {
    int j = idx & 7, lane = (idx >> 3) & 63, ks = (idx >> 9) & 7, Dt = idx >> 12;
    int k  = ks * 32 + ((lane >> 4) << 3) + j;
    int dp = Dt * 16 + (lane & 15);
    int hh = dp >> 6, d = dp & 63;
    wfrag[idx] = f2bf(W[(size_t)(hh * IN_F + k) * HD + d]);
  }
}

// ---------------- kernel 2: f1[h][n]=h·u1h, f2[h][n]=h·u2h  (one wave per row)
__global__ __launch_bounds__(256) void gat_f12_kernel(const float* __restrict__ hmat,
    const float* __restrict__ u, float* __restrict__ f1, float* __restrict__ f2)
{
  int n = blockIdx.x * 4 + (threadIdx.x >> 6);
  int l = threadIdx.x & 63;
  float4 hv = *(const float4*)(hmat + (size_t)n * IN_F + l * 4);
  float s[4];
#pragma unroll
  for (int q = 0; q < 4; ++q) {
    float4 uv = *(const float4*)(u + q * IN_F + l * 4);
    s[q] = hv.x * uv.x + hv.y * uv.y + hv.z * uv.z + hv.w * uv.w;
  }
#pragma unroll
  for (int off = 1; off < 64; off <<= 1) {
#pragma unroll
    for (int q = 0; q < 4; ++q) s[q] += __shfl_xor(s[q], off);
  }
  if (l == 0) {
    f1[n] = s[0];           f2[n] = s[1];
    f1[N_NODES + n] = s[2]; f2[N_NODES + n] = s[3];
  }
}

// ---------------- kernel 3: per-head max of f2 (softmax stability bound)
__global__ void gat_f2max_kernel(const float* __restrict__ f2, float* __restrict__ f2m)
{
  int h = blockIdx.x;
  float m = -1e30f;
  for (int i = threadIdx.x; i < N_NODES; i += 256) m = fmaxf(m, f2[h * N_NODES + i]);
#pragma unroll
  for (int off = 1; off < 64; off <<= 1) m = fmaxf(m, __shfl_xor(m, off));
  __shared__ float red[4];
  if ((threadIdx.x & 63) == 0) red[threadIdx.x >> 6] = m;
  __syncthreads();
  if (threadIdx.x == 0) f2m[h] = fmaxf(fmaxf(red[0], red[1]), fmaxf(red[2], red[3]));
}

// ---------------- kernel 4: Wh = h @ W' (bf16 MFMA), epilogue stores bf16 in
// the attention kernel's B-fragment order: whb[h][Tm][s][D][lane][j]
__global__ __launch_bounds__(256) void gat_wh_kernel(const float* __restrict__ hmat,
    const unsigned short* __restrict__ wfrag, unsigned short* __restrict__ whb)
{
  int tid = threadIdx.x;
  int w = tid >> 6, l = tid & 63;
  int n0 = blockIdx.x * 64;
  int row = n0 + w * 16 + (l & 15);
  f32x4 acc[8] = {};
#pragma unroll
  for (int ks = 0; ks < 8; ++ks) {
    const float* ap = hmat + (size_t)row * IN_F + ks * 32 + ((l >> 4) << 3);
    float av[8];
    *(float4*)&av[0] = *(const float4*)ap;
    *(float4*)&av[4] = *(const float4*)(ap + 4);
    bf16x8s af;
#pragma unroll
    for (int j = 0; j < 8; ++j) af[j] = (short)f2bf(av[j]);
#pragma unroll
    for (int Dt = 0; Dt < 8; ++Dt) {
      bf16x8s bfv = *(const bf16x8s*)(wfrag + ((size_t)(Dt * 8 + ks) * 64 + l) * 8);
      acc[Dt] = __builtin_amdgcn_mfma_f32_16x16x32_bf16(af, bfv, acc[Dt], 0, 0, 0);
    }
  }
  // D-frag (row=(l>>4)*4+r, col=l&15) -> B-frag position for the attn kernel
  int Tm = blockIdx.x;
  int s  = w >> 1;
  int lb = ((w & 1) * 2 + ((l >> 4) >> 1)) * 16 + (l & 15);
  int jh = (l >> 4) & 1;
#pragma unroll
  for (int Dt = 0; Dt < 8; ++Dt) {
    int hh = Dt >> 2, D = Dt & 3;
    ushort4 pk;
    pk.x = f2bf(acc[Dt][0]); pk.y = f2bf(acc[Dt][1]);
    pk.z = f2bf(acc[Dt][2]); pk.w = f2bf(acc[Dt][3]);
    size_t off = ((((size_t)(hh * 128 + Tm) * 2 + s) * 4 + D) * 64 + lb) * 8 + jh * 4;
    *(ushort4*)(whb + off) = pk;
  }
}

// ---------------- kernel 5: streaming masked-softmax + PV (MFMA), fixed row-max
__global__ __launch_bounds__(256) void gat_attn_kernel(
    const int* __restrict__ adj, const unsigned short* __restrict__ whb,
    const float* __restrict__ f1, const float* __restrict__ f2,
    const float* __restrict__ f2max, float* __restrict__ Opart, float* __restrict__ Lpart)
{
  int bx = blockIdx.x;                 // grid = NH*128*MS
  int split = bx & (MS - 1);
  int T = (bx >> 2) & 127;
  int h = bx >> 9;
  int tid = threadIdx.x;
  int w = tid >> 6, l = tid & 63;
  int n0 = T * 64;
  int row = n0 + w * 16 + (l & 15);

  float f1v = f1[h * N_NODES + row];
  float tm  = f1v + f2max[h];
  float mrow = fmaxf(tm, ALPHA * tm);  // lrelu(f1+f2max) >= all e in this row
  const float* f2h = f2 + h * N_NODES;
  const int* adjr  = adj + (size_t)row * N_NODES;

  __shared__ uint4 ldsbuf[512];        // 8 KB staged Wh fragment tile
  unsigned short* lds = (unsigned short*)ldsbuf;

  f32x4 acc[4] = {};
  float lsum = 0.f;
  int mbase = split * (N_NODES / MS);

  for (int mt = 0; mt < (N_NODES / MS) / 64; ++mt) {
    int m0 = mbase + mt * 64;
    const uint4* src = (const uint4*)(whb + (size_t)(h * 128 + (m0 >> 6)) * 4096);

    // P fragments (A-operand): lane l holds P[row=l&15][k=(l>>4)*8+j]
    bf16x8s af[2];
#pragma unroll
    for (int s = 0; s < 2; ++s) {
      int mk = m0 + s * 32 + ((l >> 4) << 3);
      int aj[8]; float g[8];
      *(int4*)&aj[0]   = *(const int4*)(adjr + mk);
      *(int4*)&aj[4]   = *(const int4*)(adjr + mk + 4);
      *(float4*)&g[0]  = *(const float4*)(f2h + mk);
      *(float4*)&g[4]  = *(const float4*)(f2h + mk + 4);
      float ps = 0.f;
#pragma unroll
      for (int j = 0; j < 8; ++j) {
        float e = f1v + g[j];
        e = fmaxf(e, ALPHA * e);                       // leaky_relu
        float p = (aj[j] > 0) ? __expf(e - mrow) : 0.f; // e-mrow <= 0 always
        ps += p;
        af[s][j] = (short)f2bf(p);
      }
      lsum += ps;
    }

    __syncthreads();                   // previous tile's reads done
    ((uint4*)lds)[tid]       = src[tid];
    ((uint4*)lds)[tid + 256] = src[tid + 256];
    __syncthreads();

#pragma unroll
    for (int s = 0; s < 2; ++s) {
#pragma unroll
      for (int D = 0; D < 4; ++D) {
        bf16x8s bfv = *(const bf16x8s*)&lds[(s * 4 + D) * 512 + l * 8];
        acc[D] = __builtin_amdgcn_mfma_f32_16x16x32_bf16(af[s], bfv, acc[D], 0, 0, 0);
      }
    }
  }

  // denominators: sum the 4 lanes holding the same row
  lsum += __shfl_xor(lsum, 16);
  lsum += __shfl_xor(lsum, 32);
  if (l < 16) Lpart[((size_t)(split * NH + h) << 13) + n0 + w * 16 + l] = lsum;

  float* op = Opart + (size_t)(split * NH + h) * N_NODES * HD;
#pragma unroll
  for (int D = 0; D < 4; ++D) {
#pragma unroll
    for (int r = 0; r < 4; ++r) {
      int orow = n0 + w * 16 + ((l >> 4) << 2) + r;   // C/D: row=(lane>>4)*4+reg
      op[(size_t)orow * HD + D * 16 + (l & 15)] = acc[D][r];
    }
  }
}

// ---------------- kernel 6: combine splits, normalize, ELU, transpose layout
__global__ __launch_bounds__(256) void gat_final_kernel(const float* __restrict__ Opart,
    const float* __restrict__ Lpart, float* __restrict__ out)
{
  int idx = blockIdx.x * 256 + threadIdx.x;
  int n = idx >> 7, c = idx & 127;
  int h = c >> 6, d = c & 63;
  float v = 0.f, ls = 0.f;
#pragma unroll
  for (int sp = 0; sp < MS; ++sp) {
    v  += Opart[((size_t)(sp * NH + h) * N_NODES + n) * HD + d];
    ls += Lpart[(size_t)(sp * NH + h) * N_NODES + n];
  }
  float r = v / fmaxf(ls, 1e-30f);
  out[idx] = (r > 0.f) ? r : (__expf(r) - 1.f);
}

extern "C" void kernel_launch(void* const* d_in, const int* in_sizes, int n_in,
                              void* d_out, int out_size, void* d_ws, size_t ws_size,
                              hipStream_t stream)
{
  const float* hmat = (const float*)d_in[0];
  const int*   adj  = (const int*)d_in[1];
  const float* W    = (const float*)d_in[2];
  const float* a    = (const float*)d_in[3];
  float* out = (float*)d_out;
  char* ws = (char*)d_ws;

  float* u             = (float*)(ws + OFF_U);
  unsigned short* wfrg = (unsigned short*)(ws + OFF_WFRAG);
  float* f1            = (float*)(ws + OFF_F1);
  float* f2            = (float*)(ws + OFF_F2);
  float* f2m           = (float*)(ws + OFF_F2MAX);
  unsigned short* whb  = (unsigned short*)(ws + OFF_WHB);
  float* Opart         = (float*)(ws + OFF_OP);
  float* Lpart         = (float*)(ws + OFF_LP);

  gat_prep_kernel <<<1, 256, 0, stream>>>(W, a, u, wfrg);
  gat_f12_kernel  <<<N_NODES / 4, 256, 0, stream>>>(hmat, u, f1, f2);
  gat_f2max_kernel<<<NH, 256, 0, stream>>>(f2, f2m);
  gat_wh_kernel   <<<N_NODES / 64, 256, 0, stream>>>(hmat, wfrg, whb);
  gat_attn_kernel <<<NH * 128 * MS, 256, 0, stream>>>(adj, whb, f1, f2, f2m, Opart, Lpart);
  gat_final_kernel<<<out_size / 256, 256, 0, stream>>>(Opart, Lpart, out);
}

// Round 2
// 146.432 us; speedup vs baseline: 1.0864x; 1.0864x over previous
//
#include <hip/hip_runtime.h>
#include <stdint.h>

#define N_NODES 8192
#define IN_F    256
#define HD      64
#define NH      2
#define MS      4      // m-splits per row-block
#define NT      ((N_NODES / MS) / 64)   // 32 m-tiles per block
#define ALPHA   0.2f

typedef __attribute__((ext_vector_type(8))) short bf16x8s;
typedef __attribute__((ext_vector_type(4))) float f32x4;

// ws layout (bytes)
#define OFF_U      0          // u[h][v][256] f32                   : 4 KB
#define OFF_WFRAG  4096       // W frag-order [8][8][64][8] bf16    : 64 KB
#define OFF_F1     69632      // f1[2][8192] f32                    : 64 KB
#define OFF_F2     135168     // f2[2][8192] f32                    : 64 KB
#define OFF_F2MAX  200704     // f2max[2] f32 (+pad)
#define OFF_WHB    200960     // Wh frag-order [2][128][2][4][64][8] bf16 : 2 MB
#define OFF_OP     2298112    // O partials [MS][2][8192][64] f32   : 16 MB
#define OFF_LP     19075328   // L partials [MS][2][8192] f32       : 256 KB

__device__ __forceinline__ unsigned short f2bf(float x) {
  union { float f; uint32_t u; } c; c.f = x;
  uint32_t r = c.u + 0x7FFFu + ((c.u >> 16) & 1u);   // RNE
  return (unsigned short)(r >> 16);
}

// ---------------- kernel 1: u = W·a (f32) + W repacked to B-fragment order (bf16)
__global__ void gat_prep_kernel(const float* __restrict__ W, const float* __restrict__ a,
                                float* __restrict__ u, unsigned short* __restrict__ wfrag)
{
  int t = threadIdx.x;
  for (int idx = t; idx < NH * 2 * IN_F; idx += 256) {
    int i = idx & 255, v = (idx >> 8) & 1, h = idx >> 9;
    const float* Wp = W + (size_t)(h * IN_F + i) * HD;
    const float* ap = a + h * 2 * HD + v * HD;
    float s = 0.f;
    for (int d = 0; d < HD; ++d) s += Wp[d] * ap[d];
    u[(h * 2 + v) * IN_F + i] = s;
  }
  // wfrag[Dt(8)][ks(8)][lane(64)][j(8)]: B[k][col] with k=ks*32+(lane>>4)*8+j, col=lane&15
  for (int idx = t; idx < 8 * 8 * 64 * 8; idx += 256) {
    int j = idx & 7, lane = (idx >> 3) & 63, ks = (idx >> 9) & 7, Dt = idx >> 12;
    int k  = ks * 32 + ((lane >> 4) << 3) + j;
    int dp = Dt * 16 + (lane & 15);
    int hh = dp >> 6, d = dp & 63;
    wfrag[idx] = f2bf(W[(size_t)(hh * IN_F + k) * HD + d]);
  }
}

// ---------------- kernel 2: f1[h][n]=h·u1h, f2[h][n]=h·u2h  (one wave per row)
__global__ __launch_bounds__(256) void gat_f12_kernel(const float* __restrict__ hmat,
    const float* __restrict__ u, float* __restrict__ f1, float* __restrict__ f2)
{
  int n = blockIdx.x * 4 + (threadIdx.x >> 6);
  int l = threadIdx.x & 63;
  float4 hv = *(const float4*)(hmat + (size_t)n * IN_F + l * 4);
  float s[4];
#pragma unroll
  for (int q = 0; q < 4; ++q) {
    float4 uv = *(const float4*)(u + q * IN_F + l * 4);
    s[q] = hv.x * uv.x + hv.y * uv.y + hv.z * uv.z + hv.w * uv.w;
  }
#pragma unroll
  for (int off = 1; off < 64; off <<= 1) {
#pragma unroll
    for (int q = 0; q < 4; ++q) s[q] += __shfl_xor(s[q], off);
  }
  if (l == 0) {
    f1[n] = s[0];           f2[n] = s[1];
    f1[N_NODES + n] = s[2]; f2[N_NODES + n] = s[3];
  }
}

// ---------------- kernel 3: per-head max of f2 (softmax stability bound)
__global__ void gat_f2max_kernel(const float* __restrict__ f2, float* __restrict__ f2m)
{
  int h = blockIdx.x;
  float m = -1e30f;
  for (int i = threadIdx.x; i < N_NODES; i += 256) m = fmaxf(m, f2[h * N_NODES + i]);
#pragma unroll
  for (int off = 1; off < 64; off <<= 1) m = fmaxf(m, __shfl_xor(m, off));
  __shared__ float red[4];
  if ((threadIdx.x & 63) == 0) red[threadIdx.x >> 6] = m;
  __syncthreads();
  if (threadIdx.x == 0) f2m[h] = fmaxf(fmaxf(red[0], red[1]), fmaxf(red[2], red[3]));
}

// ---------------- kernel 4: Wh = h @ W' (bf16 MFMA), epilogue stores bf16 in
// the attention kernel's B-fragment order: whb[h][Tm][s][D][lane][j]
__global__ __launch_bounds__(256) void gat_wh_kernel(const float* __restrict__ hmat,
    const unsigned short* __restrict__ wfrag, unsigned short* __restrict__ whb)
{
  int tid = threadIdx.x;
  int w = tid >> 6, l = tid & 63;
  int n0 = blockIdx.x * 64;
  int row = n0 + w * 16 + (l & 15);
  f32x4 acc[8] = {};
#pragma unroll
  for (int ks = 0; ks < 8; ++ks) {
    const float* ap = hmat + (size_t)row * IN_F + ks * 32 + ((l >> 4) << 3);
    float av[8];
    *(float4*)&av[0] = *(const float4*)ap;
    *(float4*)&av[4] = *(const float4*)(ap + 4);
    bf16x8s af;
#pragma unroll
    for (int j = 0; j < 8; ++j) af[j] = (short)f2bf(av[j]);
#pragma unroll
    for (int Dt = 0; Dt < 8; ++Dt) {
      bf16x8s bfv = *(const bf16x8s*)(wfrag + ((size_t)(Dt * 8 + ks) * 64 + l) * 8);
      acc[Dt] = __builtin_amdgcn_mfma_f32_16x16x32_bf16(af, bfv, acc[Dt], 0, 0, 0);
    }
  }
  // D-frag (row=(l>>4)*4+r, col=l&15) -> B-frag position for the attn kernel
  int Tm = blockIdx.x;
  int s  = w >> 1;
  int lb = ((w & 1) * 2 + ((l >> 4) >> 1)) * 16 + (l & 15);
  int jh = (l >> 4) & 1;
#pragma unroll
  for (int Dt = 0; Dt < 8; ++Dt) {
    int hh = Dt >> 2, D = Dt & 3;
    ushort4 pk;
    pk.x = f2bf(acc[Dt][0]); pk.y = f2bf(acc[Dt][1]);
    pk.z = f2bf(acc[Dt][2]); pk.w = f2bf(acc[Dt][3]);
    size_t off = ((((size_t)(hh * 128 + Tm) * 2 + s) * 4 + D) * 64 + lb) * 8 + jh * 4;
    *(ushort4*)(whb + off) = pk;
  }
}

// ---------------- kernel 5: streaming masked-softmax + PV (MFMA), fixed row-max
// 2-phase pipeline: issue-early prefetch (adj + whb tile) into registers,
// double-buffered whb LDS, write-late + ONE barrier per iteration (T14/T3-lite).
__global__ __launch_bounds__(256) void gat_attn_kernel(
    const int* __restrict__ adj, const unsigned short* __restrict__ whb,
    const float* __restrict__ f1, const float* __restrict__ f2,
    const float* __restrict__ f2max, float* __restrict__ Opart, float* __restrict__ Lpart)
{
  int bx = blockIdx.x;                 // grid = NH*128*MS
  int split = bx & (MS - 1);
  int T = (bx >> 2) & 127;
  int h = bx >> 9;
  int tid = threadIdx.x;
  int w = tid >> 6, l = tid & 63;
  int n0 = T * 64;
  int row = n0 + w * 16 + (l & 15);

  float f1v = f1[h * N_NODES + row];
  float tm  = f1v + f2max[h];
  float mrow = fmaxf(tm, ALPHA * tm);  // lrelu(f1+f2max) >= all e in this row
  const float* f2h = f2 + h * N_NODES;
  int mbase = split * (N_NODES / MS);
  const int* adjr = adj + (size_t)row * N_NODES + mbase;

  __shared__ float f2lds[2048];        // 8 KB: this block's f2 slice
  __shared__ uint4 wbuf[2][512];       // 2 x 8 KB: double-buffered Wh frag tile

  // stage f2 slice (once)
  {
    const float4* s = (const float4*)(f2h + mbase);
    ((float4*)f2lds)[tid]       = s[tid];
    ((float4*)f2lds)[tid + 256] = s[tid + 256];
  }

  const uint4* wsrc = (const uint4*)(whb + (size_t)(h * 128 + (mbase >> 6)) * 4096);
  int koff = (l >> 4) << 3;            // 0,8,16,24

  // prologue: prefetch tile 0
  int4 ra0 = *(const int4*)(adjr + koff);
  int4 ra1 = *(const int4*)(adjr + koff + 4);
  int4 ra2 = *(const int4*)(adjr + 32 + koff);
  int4 ra3 = *(const int4*)(adjr + 32 + koff + 4);
  uint4 rw0 = wsrc[tid];
  uint4 rw1 = wsrc[tid + 256];

  wbuf[0][tid]       = rw0;
  wbuf[0][tid + 256] = rw1;
  __syncthreads();

  f32x4 acc[4] = {};
  float lsum = 0.f;

#pragma unroll 2
  for (int mt = 0; mt < NT; ++mt) {
    // keep current tile's adj, then issue next tile's loads EARLY
    int aj0[8], aj1[8];
    *(int4*)&aj0[0] = ra0; *(int4*)&aj0[4] = ra1;
    *(int4*)&aj1[0] = ra2; *(int4*)&aj1[4] = ra3;
    if (mt + 1 < NT) {
      const int* ap = adjr + (mt + 1) * 64 + koff;
      ra0 = *(const int4*)ap;        ra1 = *(const int4*)(ap + 4);
      ra2 = *(const int4*)(ap + 32); ra3 = *(const int4*)(ap + 36);
      const uint4* wp = wsrc + (size_t)(mt + 1) * 512;
      rw0 = wp[tid]; rw1 = wp[tid + 256];
    }

    // P fragments (A-operand) from adj regs + f2 LDS — hides the load latency
    int fbase = mt * 64 + koff;
    bf16x8s af0, af1;
    float ps = 0.f;
    {
      float g[8];
      *(float4*)&g[0] = *(const float4*)&f2lds[fbase];
      *(float4*)&g[4] = *(const float4*)&f2lds[fbase + 4];
#pragma unroll
      for (int j = 0; j < 8; ++j) {
        float e = f1v + g[j];
        e = fmaxf(e, ALPHA * e);
        float p = (aj0[j] > 0) ? __expf(e - mrow) : 0.f;
        ps += p;
        af0[j] = (short)f2bf(p);
      }
    }
    {
      float g[8];
      *(float4*)&g[0] = *(const float4*)&f2lds[fbase + 32];
      *(float4*)&g[4] = *(const float4*)&f2lds[fbase + 36];
#pragma unroll
      for (int j = 0; j < 8; ++j) {
        float e = f1v + g[j];
        e = fmaxf(e, ALPHA * e);
        float p = (aj1[j] > 0) ? __expf(e - mrow) : 0.f;
        ps += p;
        af1[j] = (short)f2bf(p);
      }
    }
    lsum += ps;

    // MFMA phase on current LDS buffer
    const unsigned short* lb = (const unsigned short*)wbuf[mt & 1];
#pragma unroll
    for (int D = 0; D < 4; ++D) {
      bf16x8s bfv = *(const bf16x8s*)&lb[D * 512 + l * 8];
      acc[D] = __builtin_amdgcn_mfma_f32_16x16x32_bf16(af0, bfv, acc[D], 0, 0, 0);
    }
#pragma unroll
    for (int D = 0; D < 4; ++D) {
      bf16x8s bfv = *(const bf16x8s*)&lb[(4 + D) * 512 + l * 8];
      acc[D] = __builtin_amdgcn_mfma_f32_16x16x32_bf16(af1, bfv, acc[D], 0, 0, 0);
    }

    // write-late: next tile into the other buffer, then single barrier
    if (mt + 1 < NT) {
      wbuf[(mt + 1) & 1][tid]       = rw0;
      wbuf[(mt + 1) & 1][tid + 256] = rw1;
    }
    __syncthreads();
  }

  // denominators: sum the 4 lanes holding the same row
  lsum += __shfl_xor(lsum, 16);
  lsum += __shfl_xor(lsum, 32);
  if (l < 16) Lpart[((size_t)(split * NH + h) << 13) + n0 + w * 16 + l] = lsum;

  float* op = Opart + (size_t)(split * NH + h) * N_NODES * HD;
#pragma unroll
  for (int D = 0; D < 4; ++D) {
#pragma unroll
    for (int r = 0; r < 4; ++r) {
      int orow = n0 + w * 16 + ((l >> 4) << 2) + r;   // C/D: row=(lane>>4)*4+reg
      op[(size_t)orow * HD + D * 16 + (l & 15)] = acc[D][r];
    }
  }
}

// ---------------- kernel 6: combine splits, normalize, ELU, transpose layout
__global__ __launch_bounds__(256) void gat_final_kernel(const float* __restrict__ Opart,
    const float* __restrict__ Lpart, float* __restrict__ out)
{
  int idx = blockIdx.x * 256 + threadIdx.x;
  int n = idx >> 7, c = idx & 127;
  int h = c >> 6, d = c & 63;
  float v = 0.f, ls = 0.f;
#pragma unroll
  for (int sp = 0; sp < MS; ++sp) {
    v  += Opart[((size_t)(sp * NH + h) * N_NODES + n) * HD + d];
    ls += Lpart[(size_t)(sp * NH + h) * N_NODES + n];
  }
  float r = v / fmaxf(ls, 1e-30f);
  out[idx] = (r > 0.f) ? r : (__expf(r) - 1.f);
}

extern "C" void kernel_launch(void* const* d_in, const int* in_sizes, int n_in,
                              void* d_out, int out_size, void* d_ws, size_t ws_size,
                              hipStream_t stream)
{
  const float* hmat = (const float*)d_in[0];
  const int*   adj  = (const int*)d_in[1];
  const float* W    = (const float*)d_in[2];
  const float* a    = (const float*)d_in[3];
  float* out = (float*)d_out;
  char* ws = (char*)d_ws;

  float* u             = (float*)(ws + OFF_U);
  unsigned short* wfrg = (unsigned short*)(ws + OFF_WFRAG);
  float* f1            = (float*)(ws + OFF_F1);
  float* f2            = (float*)(ws + OFF_F2);
  float* f2m           = (float*)(ws + OFF_F2MAX);
  unsigned short* whb  = (unsigned short*)(ws + OFF_WHB);
  float* Opart         = (float*)(ws + OFF_OP);
  float* Lpart         = (float*)(ws + OFF_LP);

  gat_prep_kernel <<<1, 256, 0, stream>>>(W, a, u, wfrg);
  gat_f12_kernel  <<<N_NODES / 4, 256, 0, stream>>>(hmat, u, f1, f2);
  gat_f2max_kernel<<<NH, 256, 0, stream>>>(f2, f2m);
  gat_wh_kernel   <<<N_NODES / 64, 256, 0, stream>>>(hmat, wfrg, whb);
  gat_attn_kernel <<<NH * 128 * MS, 256, 0, stream>>>(adj, whb, f1, f2, f2m, Opart, Lpart);
  gat_final_kernel<<<out_size / 256, 256, 0, stream>>>(Opart, Lpart, out);
}

// Round 3
// 109.785 us; speedup vs baseline: 1.4490x; 1.3338x over previous
//
#include <hip/hip_runtime.h>
#include <stdint.h>

#define N_NODES 8192
#define IN_F    256
#define HD      64
#define NH      2
#define MS      4                        // m-splits per row-block
#define NT      ((N_NODES / MS) / 64)    // 32 m-tiles per block
#define ALPHA   0.2f

typedef __attribute__((ext_vector_type(8))) short bf16x8s;
typedef __attribute__((ext_vector_type(4))) float f32x4;

// ws layout (bytes)
#define OFF_U      0          // u[h][v][256] f32                   : 4 KB
#define OFF_WFRAG  4096       // W frag-order [8][8][64][8] bf16    : 64 KB
#define OFF_F1     69632      // f1[2][8192] f32                    : 64 KB
#define OFF_F2     135168     // f2[2][8192] f32                    : 64 KB
#define OFF_F2MAX  200704     // f2max[2] f32 (+pad)
#define OFF_G2     200960     // g2[2][8192] float2 (exp(f2),exp(a*f2)) : 128 KB
#define OFF_WHB    332032     // Wh frag-order [2][128][2][4][64][8] bf16 : 2 MB
#define OFF_OP     2429184    // O partials [MS][2][8192][64] f32   : 16 MB
#define OFF_LP     19206400   // L partials [MS][2][8192] f32       : 256 KB

__device__ __forceinline__ unsigned short f2bf(float x) {
  union { float f; uint32_t u; } c; c.f = x;
  uint32_t r = c.u + 0x7FFFu + ((c.u >> 16) & 1u);   // RNE
  return (unsigned short)(r >> 16);
}

// ---------------- kernel 1: u = W·a (f32) + W repacked to B-fragment order (bf16)
// grid = 132 blocks x 256
__global__ void gat_prep_kernel(const float* __restrict__ W, const float* __restrict__ a,
                                float* __restrict__ u, unsigned short* __restrict__ wfrag)
{
  int idx = blockIdx.x * 256 + threadIdx.x;
  if (idx < 32768) {
    // wfrag[Dt(8)][ks(8)][lane(64)][j(8)]: B[k][col], k=ks*32+(lane>>4)*8+j, col=lane&15
    int j = idx & 7, lane = (idx >> 3) & 63, ks = (idx >> 9) & 7, Dt = idx >> 12;
    int k  = ks * 32 + ((lane >> 4) << 3) + j;
    int dp = Dt * 16 + (lane & 15);
    int hh = dp >> 6, d = dp & 63;
    wfrag[idx] = f2bf(W[(size_t)(hh * IN_F + k) * HD + d]);
  } else if (idx < 32768 + NH * 2 * IN_F) {
    int i2 = idx - 32768;
    int i = i2 & 255, v = (i2 >> 8) & 1, h = i2 >> 9;
    const float* Wp = W + (size_t)(h * IN_F + i) * HD;
    const float* ap = a + h * 2 * HD + v * HD;
    float s = 0.f;
    for (int d = 0; d < HD; ++d) s += Wp[d] * ap[d];
    u[(h * 2 + v) * IN_F + i] = s;
  }
}

// ---------------- kernel 2: f1/f2 = h·u, plus per-column exp pairs G1=exp(f2),Ga=exp(a*f2)
__global__ __launch_bounds__(256) void gat_f12_kernel(const float* __restrict__ hmat,
    const float* __restrict__ u, float* __restrict__ f1, float* __restrict__ f2,
    float2* __restrict__ g2)
{
  int n = blockIdx.x * 4 + (threadIdx.x >> 6);
  int l = threadIdx.x & 63;
  float4 hv = *(const float4*)(hmat + (size_t)n * IN_F + l * 4);
  float s[4];
#pragma unroll
  for (int q = 0; q < 4; ++q) {
    float4 uv = *(const float4*)(u + q * IN_F + l * 4);
    s[q] = hv.x * uv.x + hv.y * uv.y + hv.z * uv.z + hv.w * uv.w;
  }
#pragma unroll
  for (int off = 1; off < 64; off <<= 1) {
#pragma unroll
    for (int q = 0; q < 4; ++q) s[q] += __shfl_xor(s[q], off);
  }
  if (l == 0) {
    f1[n] = s[0];           f2[n] = s[1];
    f1[N_NODES + n] = s[2]; f2[N_NODES + n] = s[3];
    g2[n]           = make_float2(__expf(s[1]), __expf(ALPHA * s[1]));
    g2[N_NODES + n] = make_float2(__expf(s[3]), __expf(ALPHA * s[3]));
  }
}

// ---------------- kernel 3: per-head max of f2 (softmax stability bound)
__global__ void gat_f2max_kernel(const float* __restrict__ f2, float* __restrict__ f2m)
{
  int h = blockIdx.x;
  float m = -1e30f;
  for (int i = threadIdx.x; i < N_NODES; i += 256) m = fmaxf(m, f2[h * N_NODES + i]);
#pragma unroll
  for (int off = 1; off < 64; off <<= 1) m = fmaxf(m, __shfl_xor(m, off));
  __shared__ float red[4];
  if ((threadIdx.x & 63) == 0) red[threadIdx.x >> 6] = m;
  __syncthreads();
  if (threadIdx.x == 0) f2m[h] = fmaxf(fmaxf(red[0], red[1]), fmaxf(red[2], red[3]));
}

// ---------------- kernel 4: Wh = h @ W' (bf16 MFMA), epilogue stores bf16 in
// the attention kernel's B-fragment order: whb[h][Tm][s][D][lane][j]
__global__ __launch_bounds__(256) void gat_wh_kernel(const float* __restrict__ hmat,
    const unsigned short* __restrict__ wfrag, unsigned short* __restrict__ whb)
{
  int tid = threadIdx.x;
  int w = tid >> 6, l = tid & 63;
  int n0 = blockIdx.x * 64;
  int row = n0 + w * 16 + (l & 15);
  f32x4 acc[8] = {};
#pragma unroll
  for (int ks = 0; ks < 8; ++ks) {
    const float* ap = hmat + (size_t)row * IN_F + ks * 32 + ((l >> 4) << 3);
    float av[8];
    *(float4*)&av[0] = *(const float4*)ap;
    *(float4*)&av[4] = *(const float4*)(ap + 4);
    bf16x8s af;
#pragma unroll
    for (int j = 0; j < 8; ++j) af[j] = (short)f2bf(av[j]);
#pragma unroll
    for (int Dt = 0; Dt < 8; ++Dt) {
      bf16x8s bfv = *(const bf16x8s*)(wfrag + ((size_t)(Dt * 8 + ks) * 64 + l) * 8);
      acc[Dt] = __builtin_amdgcn_mfma_f32_16x16x32_bf16(af, bfv, acc[Dt], 0, 0, 0);
    }
  }
  int Tm = blockIdx.x;
  int s  = w >> 1;
  int lb = ((w & 1) * 2 + ((l >> 4) >> 1)) * 16 + (l & 15);
  int jh = (l >> 4) & 1;
#pragma unroll
  for (int Dt = 0; Dt < 8; ++Dt) {
    int hh = Dt >> 2, D = Dt & 3;
    ushort4 pk;
    pk.x = f2bf(acc[Dt][0]); pk.y = f2bf(acc[Dt][1]);
    pk.z = f2bf(acc[Dt][2]); pk.w = f2bf(acc[Dt][3]);
    size_t off = ((((size_t)(hh * 128 + Tm) * 2 + s) * 4 + D) * 64 + lb) * 8 + jh * 4;
    *(ushort4*)(whb + off) = pk;
  }
}

// ---------------- kernel 5: streaming masked-softmax + PV (MFMA), BOTH heads per
// block (adj read ONCE), exp-free P via max(E1*G1, Ea*Ga), 2-deep adj prefetch.
__global__ __launch_bounds__(256) void gat_attn_kernel(
    const int* __restrict__ adj, const unsigned short* __restrict__ whb,
    const float* __restrict__ f1, const float2* __restrict__ g2,
    const float* __restrict__ f2max, float* __restrict__ Opart, float* __restrict__ Lpart)
{
  int bx = blockIdx.x;                 // grid = 128*MS
  int split = bx & (MS - 1);
  int T = bx >> 2;
  int tid = threadIdx.x;
  int w = tid >> 6, l = tid & 63;
  int n0 = T * 64;
  int row = n0 + w * 16 + (l & 15);
  int mbase = split * (N_NODES / MS);
  int koff = (l >> 4) << 3;            // 0,8,16,24

  float E1[NH], Ea[NH];
#pragma unroll
  for (int h = 0; h < NH; ++h) {
    float f1v = f1[h * N_NODES + row];
    float tm  = f1v + f2max[h];
    float mrow = fmaxf(tm, ALPHA * tm);   // lrelu(f1+f2max) >= all e in this row
    E1[h] = __expf(f1v - mrow);
    Ea[h] = __expf(ALPHA * f1v - mrow);
  }

  __shared__ float4 gl[2048];          // 32 KB: G-pairs, [h][1024 float4]
  __shared__ uint4  wbuf[1024];        // 16 KB: whb tile, both heads

  {
    const float4* s0 = (const float4*)(g2 + mbase);
    const float4* s1 = (const float4*)(g2 + N_NODES + mbase);
#pragma unroll
    for (int i = 0; i < 4; ++i) {
      gl[i * 256 + tid]        = s0[i * 256 + tid];
      gl[1024 + i * 256 + tid] = s1[i * 256 + tid];
    }
  }

  const int* adjr = adj + (size_t)row * N_NODES + mbase + koff;
  const uint4* ws0 = (const uint4*)(whb + ((size_t)(0 * 128 + (mbase >> 6))) * 4096);
  const uint4* ws1 = (const uint4*)(whb + ((size_t)(1 * 128 + (mbase >> 6))) * 4096);

  // prologue: adj 2-deep, whb 1-deep register prefetch
  int4 raA0 = *(const int4*)(adjr);      int4 raA1 = *(const int4*)(adjr + 4);
  int4 raA2 = *(const int4*)(adjr + 32); int4 raA3 = *(const int4*)(adjr + 36);
  int4 raB0 = *(const int4*)(adjr + 64); int4 raB1 = *(const int4*)(adjr + 68);
  int4 raB2 = *(const int4*)(adjr + 96); int4 raB3 = *(const int4*)(adjr + 100);
  uint4 rw0 = ws0[tid], rw1 = ws0[tid + 256];
  uint4 rw2 = ws1[tid], rw3 = ws1[tid + 256];

  f32x4 acc[NH][4] = {};
  float lsum[NH] = {0.f, 0.f};

#pragma unroll 2
  for (int mt = 0; mt < NT; ++mt) {
    __syncthreads();                   // prev tile's LDS reads done (covers gl stage at mt=0)
    wbuf[tid]       = rw0; wbuf[tid + 256] = rw1;
    wbuf[tid + 512] = rw2; wbuf[tid + 768] = rw3;

    int aj[16];
    *(int4*)&aj[0]  = raA0; *(int4*)&aj[4]  = raA1;
    *(int4*)&aj[8]  = raA2; *(int4*)&aj[12] = raA3;
    raA0 = raB0; raA1 = raB1; raA2 = raB2; raA3 = raB3;
    if (mt + 2 < NT) {
      const int* ap = adjr + (mt + 2) * 64;
      raB0 = *(const int4*)ap;        raB1 = *(const int4*)(ap + 4);
      raB2 = *(const int4*)(ap + 32); raB3 = *(const int4*)(ap + 36);
    }
    if (mt + 1 < NT) {
      const uint4* wp0 = ws0 + (size_t)(mt + 1) * 512;
      const uint4* wp1 = ws1 + (size_t)(mt + 1) * 512;
      rw0 = wp0[tid]; rw1 = wp0[tid + 256];
      rw2 = wp1[tid]; rw3 = wp1[tid + 256];
    }
    __syncthreads();                   // wbuf visible

#pragma unroll
    for (int h = 0; h < NH; ++h) {
      float E1h = E1[h], Eah = Ea[h];
      bf16x8s af[2];
#pragma unroll
      for (int s = 0; s < 2; ++s) {
        const float4* gp = &gl[h * 1024 + ((mt * 64 + s * 32 + koff) >> 1)];
        float ps = 0.f;
#pragma unroll
        for (int k = 0; k < 4; ++k) {
          float4 gv = gp[k];
          int a0 = aj[s * 8 + 2 * k], a1 = aj[s * 8 + 2 * k + 1];
          // p = exp(lrelu(f1+f2) - mrow) = max(E1*exp(f2), Ea*exp(a*f2)); <= 1 by construction
          float p0 = (a0 > 0) ? fmaxf(E1h * gv.x, Eah * gv.y) : 0.f;
          float p1 = (a1 > 0) ? fmaxf(E1h * gv.z, Eah * gv.w) : 0.f;
          ps += p0 + p1;
          af[s][2 * k]     = (short)f2bf(p0);
          af[s][2 * k + 1] = (short)f2bf(p1);
        }
        lsum[h] += ps;
      }
      const unsigned short* lb = (const unsigned short*)wbuf + h * 4096;
#pragma unroll
      for (int s = 0; s < 2; ++s)
#pragma unroll
        for (int D = 0; D < 4; ++D) {
          bf16x8s bfv = *(const bf16x8s*)&lb[(s * 4 + D) * 512 + l * 8];
          acc[h][D] = __builtin_amdgcn_mfma_f32_16x16x32_bf16(af[s], bfv, acc[h][D], 0, 0, 0);
        }
    }
  }

#pragma unroll
  for (int h = 0; h < NH; ++h) {
    float ls = lsum[h];
    ls += __shfl_xor(ls, 16);
    ls += __shfl_xor(ls, 32);
    if (l < 16) Lpart[((size_t)(split * NH + h) << 13) + n0 + w * 16 + l] = ls;
    float* op = Opart + (size_t)(split * NH + h) * N_NODES * HD;
#pragma unroll
    for (int D = 0; D < 4; ++D)
#pragma unroll
      for (int r = 0; r < 4; ++r) {
        int orow = n0 + w * 16 + ((l >> 4) << 2) + r;   // C/D: row=(lane>>4)*4+reg
        op[(size_t)orow * HD + D * 16 + (l & 15)] = acc[h][D][r];
      }
  }
}

// ---------------- kernel 6: combine splits, normalize, ELU, transpose layout
__global__ __launch_bounds__(256) void gat_final_kernel(const float* __restrict__ Opart,
    const float* __restrict__ Lpart, float* __restrict__ out)
{
  int idx = blockIdx.x * 256 + threadIdx.x;
  int n = idx >> 7, c = idx & 127;
  int h = c >> 6, d = c & 63;
  float v = 0.f, ls = 0.f;
#pragma unroll
  for (int sp = 0; sp < MS; ++sp) {
    v  += Opart[((size_t)(sp * NH + h) * N_NODES + n) * HD + d];
    ls += Lpart[(size_t)(sp * NH + h) * N_NODES + n];
  }
  float r = v / fmaxf(ls, 1e-30f);
  out[idx] = (r > 0.f) ? r : (__expf(r) - 1.f);
}

extern "C" void kernel_launch(void* const* d_in, const int* in_sizes, int n_in,
                              void* d_out, int out_size, void* d_ws, size_t ws_size,
                              hipStream_t stream)
{
  const float* hmat = (const float*)d_in[0];
  const int*   adj  = (const int*)d_in[1];
  const float* W    = (const float*)d_in[2];
  const float* a    = (const float*)d_in[3];
  float* out = (float*)d_out;
  char* ws = (char*)d_ws;

  float* u             = (float*)(ws + OFF_U);
  unsigned short* wfrg = (unsigned short*)(ws + OFF_WFRAG);
  float* f1            = (float*)(ws + OFF_F1);
  float* f2            = (float*)(ws + OFF_F2);
  float* f2m           = (float*)(ws + OFF_F2MAX);
  float2* g2           = (float2*)(ws + OFF_G2);
  unsigned short* whb  = (unsigned short*)(ws + OFF_WHB);
  float* Opart         = (float*)(ws + OFF_OP);
  float* Lpart         = (float*)(ws + OFF_LP);

  gat_prep_kernel <<<132, 256, 0, stream>>>(W, a, u, wfrg);
  gat_f12_kernel  <<<N_NODES / 4, 256, 0, stream>>>(hmat, u, f1, f2, g2);
  gat_f2max_kernel<<<NH, 256, 0, stream>>>(f2, f2m);
  gat_wh_kernel   <<<N_NODES / 64, 256, 0, stream>>>(hmat, wfrg, whb);
  gat_attn_kernel <<<128 * MS, 256, 0, stream>>>(adj, whb, f1, g2, f2m, Opart, Lpart);
  gat_final_kernel<<<out_size / 256, 256, 0, stream>>>(Opart, Lpart, out);
}

// Round 4
// 109.408 us; speedup vs baseline: 1.4540x; 1.0035x over previous
//
#include <hip/hip_runtime.h>
#include <hip/hip_bf16.h>
#include <stdint.h>

#define N_NODES 8192
#define IN_F    256
#define HD      64
#define NH      2
#define MS      8                        // m-splits (column splits)
#define NT      ((N_NODES / MS) / 64)    // 16 m-tiles per block
#define ALPHA   0.2f

typedef __attribute__((ext_vector_type(8))) short bf16x8s;
typedef __attribute__((ext_vector_type(4))) float f32x4;

// ws layout (bytes)
#define OFF_U      0          // u[h][v][256] f32                   : 4 KB
#define OFF_WFRAG  4096       // W frag-order [8][8][64][8] bf16    : 64 KB
#define OFF_F1     69632      // f1[2][8192] f32                    : 64 KB
#define OFF_F2     135168     // f2[2][8192] f32                    : 64 KB
#define OFF_F2MAX  200704     // f2max[2] f32 (+pad)
#define OFF_G2     200960     // g2[2][8192] float2                 : 128 KB
#define OFF_WHB    332032     // Wh frag-order [2][128][2][4][64][8] bf16 : 2 MB
#define OFF_OP     2429184    // O partials [MS][2][8192][64] f32   : 32 MB
#define OFF_LP     35983616   // L partials [MS][2][8192] f32       : 512 KB

__device__ __forceinline__ unsigned short f2bf(float x) {
  union { float f; uint32_t u; } c; c.f = x;
  uint32_t r = c.u + 0x7FFFu + ((c.u >> 16) & 1u);   // RNE
  return (unsigned short)(r >> 16);
}
__device__ __forceinline__ short f2bfs(float x) {
  __hip_bfloat16 b = __float2bfloat16(x);            // RNE, compiler lowers to cvt
  return __builtin_bit_cast(short, b);
}

// ---------------- kernel 1: u = W·a (f32) + W repacked to B-fragment order (bf16)
__global__ void gat_prep_kernel(const float* __restrict__ W, const float* __restrict__ a,
                                float* __restrict__ u, unsigned short* __restrict__ wfrag)
{
  int idx = blockIdx.x * 256 + threadIdx.x;
  if (idx < 32768) {
    // wfrag[Dt(8)][ks(8)][lane(64)][j(8)]: B[k][col], k=ks*32+(lane>>4)*8+j, col=lane&15
    int j = idx & 7, lane = (idx >> 3) & 63, ks = (idx >> 9) & 7, Dt = idx >> 12;
    int k  = ks * 32 + ((lane >> 4) << 3) + j;
    int dp = Dt * 16 + (lane & 15);
    int hh = dp >> 6, d = dp & 63;
    wfrag[idx] = f2bf(W[(size_t)(hh * IN_F + k) * HD + d]);
  } else if (idx < 32768 + NH * 2 * IN_F) {
    int i2 = idx - 32768;
    int i = i2 & 255, v = (i2 >> 8) & 1, h = i2 >> 9;
    const float* Wp = W + (size_t)(h * IN_F + i) * HD;
    const float* ap = a + h * 2 * HD + v * HD;
    float s = 0.f;
    for (int d = 0; d < HD; ++d) s += Wp[d] * ap[d];
    u[(h * 2 + v) * IN_F + i] = s;
  }
}

// ---------------- kernel 2: f1/f2 = h·u, plus per-column exp pairs G1=exp(f2),Ga=exp(a*f2)
__global__ __launch_bounds__(256) void gat_f12_kernel(const float* __restrict__ hmat,
    const float* __restrict__ u, float* __restrict__ f1, float* __restrict__ f2,
    float2* __restrict__ g2)
{
  int n = blockIdx.x * 4 + (threadIdx.x >> 6);
  int l = threadIdx.x & 63;
  float4 hv = *(const float4*)(hmat + (size_t)n * IN_F + l * 4);
  float s[4];
#pragma unroll
  for (int q = 0; q < 4; ++q) {
    float4 uv = *(const float4*)(u + q * IN_F + l * 4);
    s[q] = hv.x * uv.x + hv.y * uv.y + hv.z * uv.z + hv.w * uv.w;
  }
#pragma unroll
  for (int off = 1; off < 64; off <<= 1) {
#pragma unroll
    for (int q = 0; q < 4; ++q) s[q] += __shfl_xor(s[q], off);
  }
  if (l == 0) {
    f1[n] = s[0];           f2[n] = s[1];
    f1[N_NODES + n] = s[2]; f2[N_NODES + n] = s[3];
    g2[n]           = make_float2(__expf(s[1]), __expf(ALPHA * s[1]));
    g2[N_NODES + n] = make_float2(__expf(s[3]), __expf(ALPHA * s[3]));
  }
}

// ---------------- kernel 3: per-head max of f2 (softmax stability bound)
__global__ void gat_f2max_kernel(const float* __restrict__ f2, float* __restrict__ f2m)
{
  int h = blockIdx.x;
  float m = -1e30f;
  for (int i = threadIdx.x; i < N_NODES; i += 256) m = fmaxf(m, f2[h * N_NODES + i]);
#pragma unroll
  for (int off = 1; off < 64; off <<= 1) m = fmaxf(m, __shfl_xor(m, off));
  __shared__ float red[4];
  if ((threadIdx.x & 63) == 0) red[threadIdx.x >> 6] = m;
  __syncthreads();
  if (threadIdx.x == 0) f2m[h] = fmaxf(fmaxf(red[0], red[1]), fmaxf(red[2], red[3]));
}

// ---------------- kernel 4: Wh = h @ W' (bf16 MFMA), epilogue in B-frag order
__global__ __launch_bounds__(256) void gat_wh_kernel(const float* __restrict__ hmat,
    const unsigned short* __restrict__ wfrag, unsigned short* __restrict__ whb)
{
  int tid = threadIdx.x;
  int w = tid >> 6, l = tid & 63;
  int n0 = blockIdx.x * 64;
  int row = n0 + w * 16 + (l & 15);
  f32x4 acc[8] = {};
#pragma unroll
  for (int ks = 0; ks < 8; ++ks) {
    const float* ap = hmat + (size_t)row * IN_F + ks * 32 + ((l >> 4) << 3);
    float av[8];
    *(float4*)&av[0] = *(const float4*)ap;
    *(float4*)&av[4] = *(const float4*)(ap + 4);
    bf16x8s af;
#pragma unroll
    for (int j = 0; j < 8; ++j) af[j] = f2bfs(av[j]);
#pragma unroll
    for (int Dt = 0; Dt < 8; ++Dt) {
      bf16x8s bfv = *(const bf16x8s*)(wfrag + ((size_t)(Dt * 8 + ks) * 64 + l) * 8);
      acc[Dt] = __builtin_amdgcn_mfma_f32_16x16x32_bf16(af, bfv, acc[Dt], 0, 0, 0);
    }
  }
  int Tm = blockIdx.x;
  int s  = w >> 1;
  int lb = ((w & 1) * 2 + ((l >> 4) >> 1)) * 16 + (l & 15);
  int jh = (l >> 4) & 1;
#pragma unroll
  for (int Dt = 0; Dt < 8; ++Dt) {
    int hh = Dt >> 2, D = Dt & 3;
    ushort4 pk;
    pk.x = f2bf(acc[Dt][0]); pk.y = f2bf(acc[Dt][1]);
    pk.z = f2bf(acc[Dt][2]); pk.w = f2bf(acc[Dt][3]);
    size_t off = ((((size_t)(hh * 128 + Tm) * 2 + s) * 4 + D) * 64 + lb) * 8 + jh * 4;
    *(ushort4*)(whb + off) = pk;
  }
}

#define LOADADJ(d0, d1, d2, d3, p, base) \
  d0 = *(const int4*)((p) + (base));      d1 = *(const int4*)((p) + (base) + 4); \
  d2 = *(const int4*)((p) + (base) + 32); d3 = *(const int4*)((p) + (base) + 36);

// ---------------- kernel 5: streaming masked-softmax + PV. Both heads AND
// 2 row-groups (32 rows) per wave: bfv/gl LDS reads amortized over 2x rows.
__global__ __launch_bounds__(256, 2) void gat_attn_kernel(
    const int* __restrict__ adj, const unsigned short* __restrict__ whb,
    const float* __restrict__ f1, const float2* __restrict__ g2,
    const float* __restrict__ f2max, float* __restrict__ Opart, float* __restrict__ Lpart)
{
  int bx = blockIdx.x;                 // grid = 64*MS
  int split = bx & (MS - 1);
  int T = bx >> 3;
  int tid = threadIdx.x;
  int w = tid >> 6, l = tid & 63;
  int n0 = T * 128;
  int rbase = n0 + w * 16 + (l & 15);  // row-group 0; rg1 = rbase+64
  int mbase = split * (N_NODES / MS);
  int koff = (l >> 4) << 3;

  float E1[NH][2], Ea[NH][2];
#pragma unroll
  for (int h = 0; h < NH; ++h)
#pragma unroll
    for (int rg = 0; rg < 2; ++rg) {
      float f1v = f1[h * N_NODES + rbase + rg * 64];
      float tm  = f1v + f2max[h];
      float mrow = fmaxf(tm, ALPHA * tm);
      E1[h][rg] = __expf(f1v - mrow);
      Ea[h][rg] = __expf(ALPHA * f1v - mrow);
    }

  __shared__ float4 gl[2][512];        // 16 KB: G-pairs per head (1024 cols)
  __shared__ uint4  wbuf[1024];        // 16 KB: whb tile, both heads

  {
    const float4* s0 = (const float4*)(g2 + mbase);
    const float4* s1 = (const float4*)(g2 + N_NODES + mbase);
    gl[0][tid] = s0[tid]; gl[0][tid + 256] = s0[tid + 256];
    gl[1][tid] = s1[tid]; gl[1][tid + 256] = s1[tid + 256];
  }

  const int* adjr0 = adj + (size_t)rbase * N_NODES + mbase + koff;
  const int* adjr1 = adjr0 + (size_t)64 * N_NODES;
  const uint4* ws0 = (const uint4*)(whb + ((size_t)(mbase >> 6)) * 4096);
  const uint4* ws1 = (const uint4*)(whb + ((size_t)(128 + (mbase >> 6))) * 4096);

  // prologue: adj 2-deep (cur + next), whb 1-deep register prefetch
  int4 cA0, cA1, cA2, cA3, cB0, cB1, cB2, cB3;
  int4 nA0, nA1, nA2, nA3, nB0, nB1, nB2, nB3;
  LOADADJ(cA0, cA1, cA2, cA3, adjr0, 0);
  LOADADJ(cB0, cB1, cB2, cB3, adjr1, 0);
  LOADADJ(nA0, nA1, nA2, nA3, adjr0, 64);
  LOADADJ(nB0, nB1, nB2, nB3, adjr1, 64);
  uint4 rw0 = ws0[tid], rw1 = ws0[tid + 256];
  uint4 rw2 = ws1[tid], rw3 = ws1[tid + 256];

  f32x4 acc[NH][2][4] = {};
  float lsum[NH][2] = {};

  for (int mt = 0; mt < NT; ++mt) {
    __syncthreads();                   // prev tile's reads done (covers gl at mt=0)
    wbuf[tid]       = rw0; wbuf[tid + 256] = rw1;
    wbuf[tid + 512] = rw2; wbuf[tid + 768] = rw3;
    if (mt + 1 < NT) {                 // issue-early: next whb tile
      const uint4* wp0 = ws0 + (size_t)(mt + 1) * 512;
      const uint4* wp1 = ws1 + (size_t)(mt + 1) * 512;
      rw0 = wp0[tid]; rw1 = wp0[tid + 256];
      rw2 = wp1[tid]; rw3 = wp1[tid + 256];
    }
    __syncthreads();                   // wbuf visible

    int ajA[16], ajB[16];
    *(int4*)&ajA[0] = cA0; *(int4*)&ajA[4]  = cA1;
    *(int4*)&ajA[8] = cA2; *(int4*)&ajA[12] = cA3;
    *(int4*)&ajB[0] = cB0; *(int4*)&ajB[4]  = cB1;
    *(int4*)&ajB[8] = cB2; *(int4*)&ajB[12] = cB3;

#pragma unroll
    for (int h = 0; h < NH; ++h) {
      bf16x8s afA[2], afB[2];
#pragma unroll
      for (int s = 0; s < 2; ++s) {
        const float4* gp = &gl[h][(mt * 64 + s * 32 + koff) >> 1];
        float psA = 0.f, psB = 0.f;
#pragma unroll
        for (int k = 0; k < 4; ++k) {
          float4 gv = gp[k];
          float m1x = E1[h][0] * gv.x, max_ = Ea[h][0] * gv.y;
          float pA0 = (ajA[s * 8 + 2 * k]     > 0) ? fmaxf(m1x, max_) : 0.f;
          float m1z = E1[h][0] * gv.z, maz = Ea[h][0] * gv.w;
          float pA1 = (ajA[s * 8 + 2 * k + 1] > 0) ? fmaxf(m1z, maz) : 0.f;
          float n1x = E1[h][1] * gv.x, nax = Ea[h][1] * gv.y;
          float pB0 = (ajB[s * 8 + 2 * k]     > 0) ? fmaxf(n1x, nax) : 0.f;
          float n1z = E1[h][1] * gv.z, naz = Ea[h][1] * gv.w;
          float pB1 = (ajB[s * 8 + 2 * k + 1] > 0) ? fmaxf(n1z, naz) : 0.f;
          psA += pA0 + pA1;  psB += pB0 + pB1;
          afA[s][2 * k] = f2bfs(pA0); afA[s][2 * k + 1] = f2bfs(pA1);
          afB[s][2 * k] = f2bfs(pB0); afB[s][2 * k + 1] = f2bfs(pB1);
        }
        lsum[h][0] += psA; lsum[h][1] += psB;
      }
      const unsigned short* lb = (const unsigned short*)wbuf + h * 4096;
#pragma unroll
      for (int s = 0; s < 2; ++s)
#pragma unroll
        for (int D = 0; D < 4; ++D) {
          bf16x8s bfv = *(const bf16x8s*)&lb[(s * 4 + D) * 512 + l * 8];
          acc[h][0][D] = __builtin_amdgcn_mfma_f32_16x16x32_bf16(afA[s], bfv, acc[h][0][D], 0, 0, 0);
          acc[h][1][D] = __builtin_amdgcn_mfma_f32_16x16x32_bf16(afB[s], bfv, acc[h][1][D], 0, 0, 0);
        }
    }

    // shift prefetch pipeline; issue tile mt+2 adj loads (in flight a full iter)
    cA0 = nA0; cA1 = nA1; cA2 = nA2; cA3 = nA3;
    cB0 = nB0; cB1 = nB1; cB2 = nB2; cB3 = nB3;
    if (mt + 2 < NT) {
      LOADADJ(nA0, nA1, nA2, nA3, adjr0, (mt + 2) * 64);
      LOADADJ(nB0, nB1, nB2, nB3, adjr1, (mt + 2) * 64);
    }
  }

#pragma unroll
  for (int h = 0; h < NH; ++h)
#pragma unroll
    for (int rg = 0; rg < 2; ++rg) {
      float ls = lsum[h][rg];
      ls += __shfl_xor(ls, 16);
      ls += __shfl_xor(ls, 32);
      if (l < 16) Lpart[((size_t)(split * NH + h) << 13) + n0 + rg * 64 + w * 16 + l] = ls;
      float* op = Opart + (size_t)(split * NH + h) * N_NODES * HD;
#pragma unroll
      for (int D = 0; D < 4; ++D)
#pragma unroll
        for (int r = 0; r < 4; ++r) {
          int orow = n0 + rg * 64 + w * 16 + ((l >> 4) << 2) + r;
          op[(size_t)orow * HD + D * 16 + (l & 15)] = acc[h][rg][D][r];
        }
    }
}

// ---------------- kernel 6: combine splits, normalize, ELU, transpose layout
__global__ __launch_bounds__(256) void gat_final_kernel(const float* __restrict__ Opart,
    const float* __restrict__ Lpart, float* __restrict__ out)
{
  int idx = blockIdx.x * 256 + threadIdx.x;
  int n = idx >> 7, c = idx & 127;
  int h = c >> 6, d = c & 63;
  float v = 0.f, ls = 0.f;
#pragma unroll
  for (int sp = 0; sp < MS; ++sp) {
    v  += Opart[((size_t)(sp * NH + h) * N_NODES + n) * HD + d];
    ls += Lpart[(size_t)(sp * NH + h) * N_NODES + n];
  }
  float r = v / fmaxf(ls, 1e-30f);
  out[idx] = (r > 0.f) ? r : (__expf(r) - 1.f);
}

extern "C" void kernel_launch(void* const* d_in, const int* in_sizes, int n_in,
                              void* d_out, int out_size, void* d_ws, size_t ws_size,
                              hipStream_t stream)
{
  const float* hmat = (const float*)d_in[0];
  const int*   adj  = (const int*)d_in[1];
  const float* W    = (const float*)d_in[2];
  const float* a    = (const float*)d_in[3];
  float* out = (float*)d_out;
  char* ws = (char*)d_ws;

  float* u             = (float*)(ws + OFF_U);
  unsigned short* wfrg = (unsigned short*)(ws + OFF_WFRAG);
  float* f1            = (float*)(ws + OFF_F1);
  float* f2            = (float*)(ws + OFF_F2);
  float* f2m           = (float*)(ws + OFF_F2MAX);
  float2* g2           = (float2*)(ws + OFF_G2);
  unsigned short* whb  = (unsigned short*)(ws + OFF_WHB);
  float* Opart         = (float*)(ws + OFF_OP);
  float* Lpart         = (float*)(ws + OFF_LP);

  gat_prep_kernel <<<132, 256, 0, stream>>>(W, a, u, wfrg);
  gat_f12_kernel  <<<N_NODES / 4, 256, 0, stream>>>(hmat, u, f1, f2, g2);
  gat_f2max_kernel<<<NH, 256, 0, stream>>>(f2, f2m);
  gat_wh_kernel   <<<N_NODES / 64, 256, 0, stream>>>(hmat, wfrg, whb);
  gat_attn_kernel <<<64 * MS, 256, 0, stream>>>(adj, whb, f1, g2, f2m, Opart, Lpart);
  gat_final_kernel<<<out_size / 256, 256, 0, stream>>>(Opart, Lpart, out);
}